// Round 2
// baseline (195.802 us; speedup 1.0000x reference)
//
#include <hip/hip_runtime.h>

// Sinkhorn, 128 x (256x256) f32, 15 fixed iterations — matrix-scaling form.
//
// y_k = diag(a) X diag(b). Per reference iteration:
//   b' = 1/(X^T a)   (div_no_nan -> 0 on zero sum)
//   a' = 1/(X b')
// so the 8x8 register tile is read-only during iterations; the two diagonal
// scalings are applied once at the end. 2 barriers/iter (was 3), ~150 VALU
// ops/thread/iter (was ~280).
//
// One 1024-thread block per matrix; thread (tr,tc) owns rows 8tr.., cols 8tc..
// Column reduce: in-thread 8-FMA chains -> shfl_xor(32) pair-combine ->
// 16 partials/col in LDS (XOR-swizzled, conflict-free) -> 256 finisher
// threads (1 wave/SIMD) tree-sum + rcp. Row reduce: width-32 shuffle
// butterfly (no LDS, result broadcast).

#define SK_ITERS 15

__device__ __forceinline__ float guarded_rcp(float s) {
    // tf.divide_no_nan semantics for 1/s
    return (s == 0.f) ? 0.f : __builtin_amdgcn_rcpf(s);
}

__global__ __launch_bounds__(1024, 4)
void sinkhorn_kernel(const float* __restrict__ xg, float* __restrict__ outg) {
    const int tid  = threadIdx.x;
    const int tr   = tid >> 5;        // row band (rows 8tr..8tr+7)
    const int tc   = tid & 31;        // col band (cols 8tc..8tc+7)
    const int key  = tc >> 2;         // XOR swizzle key 0..7
    const int wv   = tid >> 6;        // wave id 0..15
    const int half = (tid >> 5) & 1;  // which 32-lane half of the wave

    const float* __restrict__ xb = xg   + (size_t)blockIdx.x * 65536;
    float*       __restrict__ ob = outg + (size_t)blockIdx.x * 65536;

    __shared__ float partA[16][256];  // 16 KB: per-wave column partials (swizzled)
    __shared__ float brcp[256];       //  1 KB: per-column 1/colsum (swizzled)

    // ---- load 8x8 tile into registers; stays read-only for all 15 iters ----
    float x[8][8];
#pragma unroll
    for (int i = 0; i < 8; ++i) {
        const float4* p = (const float4*)(xb + (tr * 8 + i) * 256 + tc * 8);
        float4 u = p[0], w = p[1];
        x[i][0] = u.x; x[i][1] = u.y; x[i][2] = u.z; x[i][3] = u.w;
        x[i][4] = w.x; x[i][5] = w.y; x[i][6] = w.z; x[i][7] = w.w;
    }

    float a[8];
#pragma unroll
    for (int i = 0; i < 8; ++i) a[i] = 1.f;   // x_0 = diag(1) X diag(*)
    float b[8];

    // finisher's swizzled column index (valid for tid < 256):
    // s2(c) = (c & ~7) | ((c & 7) ^ ((c >> 5) & 7)) — same swizzle as writers.
    const int fidx = (tid & ~7) | ((tid & 7) ^ ((tid >> 5) & 7));

    for (int it = 0; it < SK_ITERS; ++it) {
        // ======== column phase: p_j = sum_i a_i * x_ij ========
        float p[8];
#pragma unroll
        for (int j = 0; j < 8; ++j) {
            float s = a[0] * x[0][j];
#pragma unroll
            for (int i = 1; i < 8; ++i) s = fmaf(a[i], x[i][j], s);
            p[j] = s;
        }
        // combine the two row-bands sharing this wave (tr pairs): 32 -> 16 partials
#pragma unroll
        for (int j = 0; j < 8; ++j) p[j] += __shfl_xor(p[j], 32, 64);
        // both halves now hold identical p[0..7]; split the 8 writes 4/4.
        // Bank: 8*(tc&3) + (j^key) [^4 for the upper half] — 2 lanes/bank = free.
        {
            const int j0 = half * 4;
#pragma unroll
            for (int q = 0; q < 4; ++q) {
                const int j = j0 + q;
                partA[wv][tc * 8 + (j ^ key)] = p[j];
            }
        }
        __syncthreads();

        // ---- finisher: waves 0-3 (one per SIMD) reduce 16 partials + rcp ----
        if (tid < 256) {
            float t[16];
#pragma unroll
            for (int w = 0; w < 16; ++w) t[w] = partA[w][fidx];
#pragma unroll
            for (int st = 8; st >= 1; st >>= 1)
#pragma unroll
                for (int w = 0; w < st; ++w) t[w] += t[w + st];
            brcp[fidx] = guarded_rcp(t[0]);   // b'_col = div_no_nan(1, colsum)
        }
        __syncthreads();

        // ======== row phase: rs_i = sum_j x_ij * b'_j ========
#pragma unroll
        for (int j = 0; j < 8; ++j) b[j] = brcp[tc * 8 + (j ^ key)];

        float rs[8];
#pragma unroll
        for (int i = 0; i < 8; ++i) {
            float s = x[i][0] * b[0];
#pragma unroll
            for (int j = 1; j < 8; ++j) s = fmaf(x[i][j], b[j], s);
            rs[i] = s;
        }
        // width-32 butterfly across the col-groups of this row band
#pragma unroll
        for (int m = 16; m >= 1; m >>= 1) {
#pragma unroll
            for (int i = 0; i < 8; ++i) rs[i] += __shfl_xor(rs[i], m, 64);
        }
#pragma unroll
        for (int i = 0; i < 8; ++i) a[i] = guarded_rcp(rs[i]);
        // No extra barrier: next iter's partA writes are post-barrier-2;
        // finisher's reads were pre-barrier-2; brcp reads above complete
        // before this thread reaches the next barrier-1.
    }

    // ---- apply y_ij = a_i * x_ij * b_j once, store coalesced ----
#pragma unroll
    for (int i = 0; i < 8; ++i) {
        const float ai = a[i];
        float4 u, w;
        u.x = ai * x[i][0] * b[0]; u.y = ai * x[i][1] * b[1];
        u.z = ai * x[i][2] * b[2]; u.w = ai * x[i][3] * b[3];
        w.x = ai * x[i][4] * b[4]; w.y = ai * x[i][5] * b[5];
        w.z = ai * x[i][6] * b[6]; w.w = ai * x[i][7] * b[7];
        float4* po = (float4*)(ob + (tr * 8 + i) * 256 + tc * 8);
        po[0] = u;
        po[1] = w;
    }
}

extern "C" void kernel_launch(void* const* d_in, const int* in_sizes, int n_in,
                              void* d_out, int out_size, void* d_ws, size_t ws_size,
                              hipStream_t stream) {
    const float* x = (const float*)d_in[0];
    float* out = (float*)d_out;
    const int batches = in_sizes[0] / 65536;   // 128 for the given shape
    hipLaunchKernelGGL(sinkhorn_kernel, dim3(batches), dim3(1024), 0, stream,
                       x, out);
}

// Round 4
// 194.918 us; speedup vs baseline: 1.0045x; 1.0045x over previous
//
#include <hip/hip_runtime.h>

// Sinkhorn, 128 x (256x256) f32, 15 fixed iterations — matrix-scaling form.
//
// y = diag(a) X diag(b);  per iteration:  b' = 1/(X^T a),  a' = 1/(X b').
// The 8x8 register tile is read-only during iterations; diagonal scalings
// applied once at the end.
//
// Round-2 lesson: hipcc targeted 8 waves/SIMD (<=64 VGPR) despite
// __launch_bounds__(1024,4) being a *minimum*, and spilled the 64-float x
// tile to scratch (+32 MB WRITE_SIZE, dur 61->132us). amdgpu_waves_per_eu(4,4)
// pins occupancy at exactly 4 waves/EU -> 128-VGPR budget -> tile stays in
// registers.

#define SK_ITERS 15

__device__ __forceinline__ float guarded_rcp(float s) {
    // tf.divide_no_nan semantics for 1/s
    return (s == 0.f) ? 0.f : __builtin_amdgcn_rcpf(s);
}

__global__ __launch_bounds__(1024)
__attribute__((amdgpu_waves_per_eu(4, 4)))
void sinkhorn_kernel(const float* __restrict__ xg, float* __restrict__ outg) {
    const int tid  = threadIdx.x;
    const int tr   = tid >> 5;        // row band (rows 8tr..8tr+7)
    const int tc   = tid & 31;        // col band (cols 8tc..8tc+7)
    const int key  = tc >> 2;         // XOR swizzle key 0..7
    const int wv   = tid >> 6;        // wave id 0..15
    const int half = (tid >> 5) & 1;  // which 32-lane half of the wave

    const float* __restrict__ xb = xg   + (size_t)blockIdx.x * 65536;
    float*       __restrict__ ob = outg + (size_t)blockIdx.x * 65536;

    __shared__ float partA[16][256];  // 16 KB: per-wave column partials (swizzled)
    __shared__ float brcp[256];       //  1 KB: per-column 1/colsum (swizzled)

    // ---- load 8x8 tile into registers; read-only for all 15 iters ----
    float x[8][8];
#pragma unroll
    for (int i = 0; i < 8; ++i) {
        const float4* p = (const float4*)(xb + (tr * 8 + i) * 256 + tc * 8);
        float4 u = p[0], w = p[1];
        x[i][0] = u.x; x[i][1] = u.y; x[i][2] = u.z; x[i][3] = u.w;
        x[i][4] = w.x; x[i][5] = w.y; x[i][6] = w.z; x[i][7] = w.w;
    }

    float a[8];
#pragma unroll
    for (int i = 0; i < 8; ++i) a[i] = 1.f;   // y_0 scaling starts at identity
    float b[8];

    // finisher's swizzled column index (valid for tid < 256):
    // same mapping the writers used: c -> (c&~7) | ((c&7) ^ ((c>>5)&7))
    const int fidx = (tid & ~7) | ((tid & 7) ^ ((tid >> 5) & 7));

    for (int it = 0; it < SK_ITERS; ++it) {
        // ======== column phase: p_j = sum_i a_i * x_ij ========
        float p[8];
#pragma unroll
        for (int j = 0; j < 8; ++j) {
            float s = a[0] * x[0][j];
#pragma unroll
            for (int i = 1; i < 8; ++i) s = fmaf(a[i], x[i][j], s);
            p[j] = s;
        }
        // combine the two row-bands sharing this wave: 32 -> 16 partials/col
#pragma unroll
        for (int j = 0; j < 8; ++j) p[j] += __shfl_xor(p[j], 32, 64);
        // both halves hold identical p[0..7]; split the 8 writes 4/4.
        // Bank across lanes: 8*(tc&3) + (j^key) -> distinct mod 32 = free.
        {
            const int j0 = half * 4;
#pragma unroll
            for (int q = 0; q < 4; ++q) {
                const int j = j0 + q;
                partA[wv][tc * 8 + (j ^ key)] = p[j];
            }
        }
        __syncthreads();

        // ---- finisher: waves 0-3 (one per SIMD) reduce 16 partials + rcp ----
        if (tid < 256) {
            // paired accumulate: keeps ~8 temps live instead of 16
            float s0 = partA[0][fidx] + partA[1][fidx];
            float s1 = partA[2][fidx] + partA[3][fidx];
            float s2 = partA[4][fidx] + partA[5][fidx];
            float s3 = partA[6][fidx] + partA[7][fidx];
            s0 += partA[8][fidx]  + partA[9][fidx];
            s1 += partA[10][fidx] + partA[11][fidx];
            s2 += partA[12][fidx] + partA[13][fidx];
            s3 += partA[14][fidx] + partA[15][fidx];
            brcp[fidx] = guarded_rcp((s0 + s1) + (s2 + s3));
        }
        __syncthreads();

        // ======== row phase: rs_i = sum_j x_ij * b'_j ========
#pragma unroll
        for (int j = 0; j < 8; ++j) b[j] = brcp[tc * 8 + (j ^ key)];

        float rs[8];
#pragma unroll
        for (int i = 0; i < 8; ++i) {
            float s = x[i][0] * b[0];
#pragma unroll
            for (int j = 1; j < 8; ++j) s = fmaf(x[i][j], b[j], s);
            rs[i] = s;
        }
        // width-32 butterfly across the col-groups of this row band
#pragma unroll
        for (int m = 16; m >= 1; m >>= 1) {
#pragma unroll
            for (int i = 0; i < 8; ++i) rs[i] += __shfl_xor(rs[i], m, 64);
        }
#pragma unroll
        for (int i = 0; i < 8; ++i) a[i] = guarded_rcp(rs[i]);
        // No extra barrier needed: next iter's partA writes are post-barrier-2;
        // finisher's partA reads were pre-barrier-2; this iter's brcp reads
        // complete before this thread reaches next iter's barrier-1, and next
        // iter's brcp write happens after that barrier.
    }

    // ---- apply y_ij = a_i * x_ij * b_j once, store coalesced ----
#pragma unroll
    for (int i = 0; i < 8; ++i) {
        const float ai = a[i];
        float4 u, w;
        u.x = ai * x[i][0] * b[0]; u.y = ai * x[i][1] * b[1];
        u.z = ai * x[i][2] * b[2]; u.w = ai * x[i][3] * b[3];
        w.x = ai * x[i][4] * b[4]; w.y = ai * x[i][5] * b[5];
        w.z = ai * x[i][6] * b[6]; w.w = ai * x[i][7] * b[7];
        float4* po = (float4*)(ob + (tr * 8 + i) * 256 + tc * 8);
        po[0] = u;
        po[1] = w;
    }
}

extern "C" void kernel_launch(void* const* d_in, const int* in_sizes, int n_in,
                              void* d_out, int out_size, void* d_ws, size_t ws_size,
                              hipStream_t stream) {
    const float* x = (const float*)d_in[0];
    float* out = (float*)d_out;
    const int batches = in_sizes[0] / 65536;   // 128 for the given shape
    hipLaunchKernelGGL(sinkhorn_kernel, dim3(batches), dim3(1024), 0, stream,
                       x, out);
}

// Round 5
// 145.051 us; speedup vs baseline: 1.3499x; 1.3438x over previous
//
#include <hip/hip_runtime.h>

// Sinkhorn, 128 x (256x256) f32, 15 fixed iterations — matrix-scaling form.
//   b' = 1/(X^T a),  a' = 1/(X b');  y = diag(a) X diag(b) applied once at end.
//
// Lessons encoded here:
//  r2/r4: keeping a[8] in registers across barriers (72 persistent floats)
//         spills to scratch at hipcc's 64-VGPR target; attributes don't help.
//         -> a lives in LDS (arcp); persistent reg state = x[64] only (r1-proven).
//  r1:    __shfl_xor lowers to ds_bpermute (LDS pipe, ~120cy, 5-deep chains)
//         -> ZERO shuffles: both reductions via LDS partials + 256-thread
//            finisher, 4 barriers/iter, all accesses conflict-free b32.
//
// Layouts (all XOR-swizzled, verified 32-distinct-banks or 2-lanes/bank):
//   col partials: part[tr][8*tc + (j ^ (tc>>2))]      (32x256 f32, 32 KB)
//   row partials: part[tc][row ^ tc]                   (same buffer, reused)
//   brcp[s2(col)], s2(c) = (c&~7) | ((c&7) ^ ((c>>5)&7))
//   arcp[row] (broadcast reads)

#define SK_ITERS 15

__device__ __forceinline__ float guarded_rcp(float s) {
    // tf.divide_no_nan semantics for 1/s
    return (s == 0.f) ? 0.f : __builtin_amdgcn_rcpf(s);
}

__global__ __launch_bounds__(1024, 4)
void sinkhorn_kernel(const float* __restrict__ xg, float* __restrict__ outg) {
    const int tid = threadIdx.x;
    const int tr  = tid >> 5;      // row band: rows 8tr..8tr+7
    const int tc  = tid & 31;      // col band: cols 8tc..8tc+7
    const int key = tc >> 2;       // col-swizzle key

    const float* __restrict__ xb = xg   + (size_t)blockIdx.x * 65536;
    float*       __restrict__ ob = outg + (size_t)blockIdx.x * 65536;

    __shared__ float part[32][256];   // 32 KB, shared by col- and row-partials
    __shared__ float brcp[256];       // per-column 1/colsum (s2-swizzled)
    __shared__ float arcp[256];       // per-row    1/rowsum (linear)

    // ---- load 8x8 tile; read-only for all iterations ----
    float x[8][8];
#pragma unroll
    for (int i = 0; i < 8; ++i) {
        const float4* p = (const float4*)(xb + (tr * 8 + i) * 256 + tc * 8);
        float4 u = p[0], w = p[1];
        x[i][0] = u.x; x[i][1] = u.y; x[i][2] = u.z; x[i][3] = u.w;
        x[i][4] = w.x; x[i][5] = w.y; x[i][6] = w.z; x[i][7] = w.w;
    }

    // finisher column index (tid < 256): s2 swizzle, matches writers
    const int fcol = (tid & ~7) | ((tid & 7) ^ ((tid >> 5) & 7));

    // ---- peeled col phase, iteration 1 (a == 1): plain column partials ----
#pragma unroll
    for (int j = 0; j < 8; ++j) {
        float s = ((x[0][j] + x[1][j]) + (x[2][j] + x[3][j]))
                + ((x[4][j] + x[5][j]) + (x[6][j] + x[7][j]));
        part[tr][tc * 8 + (j ^ key)] = s;
    }

    float b[8];

#pragma unroll 1
    for (int it = 0; it < SK_ITERS; ++it) {
        __syncthreads();                                   // BAR_A
        // ---- column finisher: 32 partials -> 1/colsum (chunked 4x8) ----
        if (tid < 256) {
            float s0 = 0.f, s1 = 0.f, s2 = 0.f, s3 = 0.f;
#pragma unroll
            for (int p = 0; p < 8; ++p)   s0 += part[p][fcol];
#pragma unroll
            for (int p = 8; p < 16; ++p)  s1 += part[p][fcol];
#pragma unroll
            for (int p = 16; p < 24; ++p) s2 += part[p][fcol];
#pragma unroll
            for (int p = 24; p < 32; ++p) s3 += part[p][fcol];
            brcp[fcol] = guarded_rcp((s0 + s1) + (s2 + s3));
        }
        __syncthreads();                                   // BAR_B

        // ---- row phase: rs_i = sum_j x_ij * b_j; write row partials ----
#pragma unroll
        for (int j = 0; j < 8; ++j) b[j] = brcp[tc * 8 + (j ^ key)];
#pragma unroll
        for (int i = 0; i < 8; ++i) {
            float s = x[i][0] * b[0];
#pragma unroll
            for (int j = 1; j < 8; ++j) s = fmaf(x[i][j], b[j], s);
            const int row = tr * 8 + i;
            part[tc][row ^ tc] = s;        // overwrites col partials (safe: BAR_B)
        }
        __syncthreads();                                   // BAR_C

        // ---- row finisher: 32 partials -> 1/rowsum ----
        if (tid < 256) {
            float s0 = 0.f, s1 = 0.f, s2 = 0.f, s3 = 0.f;
#pragma unroll
            for (int p = 0; p < 8; ++p)   s0 += part[p][tid ^ p];
#pragma unroll
            for (int p = 8; p < 16; ++p)  s1 += part[p][tid ^ p];
#pragma unroll
            for (int p = 16; p < 24; ++p) s2 += part[p][tid ^ p];
#pragma unroll
            for (int p = 24; p < 32; ++p) s3 += part[p][tid ^ p];
            arcp[tid] = guarded_rcp((s0 + s1) + (s2 + s3));
        }
        __syncthreads();                                   // BAR_D

        // ---- next col phase: p_j = sum_i a_i * x_ij (a via broadcast reads) ----
        if (it < SK_ITERS - 1) {
            float a0 = arcp[tr * 8 + 0], a1 = arcp[tr * 8 + 1];
            float a2 = arcp[tr * 8 + 2], a3 = arcp[tr * 8 + 3];
            float a4 = arcp[tr * 8 + 4], a5 = arcp[tr * 8 + 5];
            float a6 = arcp[tr * 8 + 6], a7 = arcp[tr * 8 + 7];
#pragma unroll
            for (int j = 0; j < 8; ++j) {
                float s = a0 * x[0][j];
                s = fmaf(a1, x[1][j], s);
                s = fmaf(a2, x[2][j], s);
                s = fmaf(a3, x[3][j], s);
                s = fmaf(a4, x[4][j], s);
                s = fmaf(a5, x[5][j], s);
                s = fmaf(a6, x[6][j], s);
                s = fmaf(a7, x[7][j], s);
                part[tr][tc * 8 + (j ^ key)] = s;
            }
        }
    }

    // ---- epilogue: y_ij = a_i * x_ij * b_j  (b[8] live from last row phase) ----
#pragma unroll
    for (int i = 0; i < 8; ++i) {
        const float ai = arcp[tr * 8 + i];   // broadcast read, ordered by BAR_D
        float4 u, w;
        u.x = ai * x[i][0] * b[0]; u.y = ai * x[i][1] * b[1];
        u.z = ai * x[i][2] * b[2]; u.w = ai * x[i][3] * b[3];
        w.x = ai * x[i][4] * b[4]; w.y = ai * x[i][5] * b[5];
        w.z = ai * x[i][6] * b[6]; w.w = ai * x[i][7] * b[7];
        float4* po = (float4*)(ob + (tr * 8 + i) * 256 + tc * 8);
        po[0] = u;
        po[1] = w;
    }
}

extern "C" void kernel_launch(void* const* d_in, const int* in_sizes, int n_in,
                              void* d_out, int out_size, void* d_ws, size_t ws_size,
                              hipStream_t stream) {
    const float* x = (const float*)d_in[0];
    float* out = (float*)d_out;
    const int batches = in_sizes[0] / 65536;   // 128 for the given shape
    hipLaunchKernelGGL(sinkhorn_kernel, dim3(batches), dim3(1024), 0, stream,
                       x, out);
}